// Round 8
// baseline (6902.860 us; speedup 1.0000x reference)
//
#include <hip/hip_runtime.h>
#include <hip/hip_bf16.h>

// SocialLSTM forward, MI355X gfx950 — ONE fused kernel per step (33 dispatches
// total). Each block owns 16 rows end-to-end: pool -> social GEMM -> gates
// GEMM -> LSTM cell -> output. h state ping-pongs between two ws buffers.
// Dual-dtype float inputs (bf16 or f32) detected inline in prep.
// ws layout (bytes):
//   c_ws  f32[1024*64]      @ 0
//   Wt    bf16[256][4096]   @ 262144   (W_soc^T, [n][k])
//   Wgt   bf16[256][384]    @ 2359296  ([Wih;Whh]^T, [n][k])
//   bsocF f32[256]          @ 2555904
//   bgF   f32[256]          @ 2556928  (bih+bhh)
//   WoutF f32[128]          @ 2557952
//   WembF f32[128]          @ 2558464
//   bembF f32[64]           @ 2558976
//   boutF f32[2]            @ 2559232
//   flag  int               @ 2559244
//   Xc    f32[32][1024][2]  @ 2560000
//   hb0   bf16[1024][64]    @ 2822144  (h state, ping)
//   hb1   bf16[1024][64]    @ 2953216  (h state, pong)

typedef short bf16x8 __attribute__((ext_vector_type(8)));
typedef float f32x4 __attribute__((ext_vector_type(4)));

#define WS_CW    0
#define WS_WT    262144
#define WS_WGT   2359296
#define WS_BSOC  2555904
#define WS_BG    2556928
#define WS_WOUT  2557952
#define WS_WEMB  2558464
#define WS_BEMB  2558976
#define WS_BOUT  2559232
#define WS_FLAG  2559244
#define WS_XC    2560000
#define WS_HB0   2822144
#define WS_HB1   2953216

__device__ __forceinline__ float u2f(unsigned short u) {
    union { unsigned int i; float f; } v; v.i = ((unsigned int)u) << 16; return v.f;
}
__device__ __forceinline__ unsigned short f2b(float f) {
    __hip_bfloat16 hb = __float2bfloat16(f);
    return *(unsigned short*)&hb;
}
__device__ __forceinline__ float ldin(const void* p, int idx, int isf32) {
    return isf32 ? ((const float*)p)[idx] : u2f(((const unsigned short*)p)[idx]);
}
__device__ __forceinline__ int get_tpred(const int* p) {
    int v = p[0];
    if (v >= 0 && v <= 64) return v;
    float f = ((const float*)p)[0];
    if (f >= 0.f && f <= 64.f) return (int)f;
    float g = u2f(((const unsigned short*)p)[0]);
    if (g >= 0.f && g <= 64.f) return (int)g;
    return 31;
}

// ---------------- one-time prep (237 blocks, inline dtype detect) ---------
__global__ __launch_bounds__(256) void k_prep(char* __restrict__ ws,
                                              const void* __restrict__ X,
                                              const void* __restrict__ h0,
                                              const void* __restrict__ c0,
                                              const void* __restrict__ Wsoc,
                                              const void* __restrict__ Wih,
                                              const void* __restrict__ Whh,
                                              const void* __restrict__ bih,
                                              const void* __restrict__ bhh,
                                              const void* __restrict__ bsoc,
                                              const void* __restrict__ Wemb,
                                              const void* __restrict__ bemb,
                                              const void* __restrict__ Wout,
                                              const void* __restrict__ bout,
                                              void* __restrict__ out) {
    __shared__ __align__(16) unsigned short tile[32 * 264];
    __shared__ int df;
    int b = blockIdx.x, tid = threadIdx.x;
    // inline dtype detect (bf16-decode first 1024 u16 of Wsoc)
    if (tid == 0) df = 0;
    __syncthreads();
    {
        const unsigned short* p = (const unsigned short*)Wsoc;
        int loc = 0;
        #pragma unroll
        for (int k = 0; k < 4; k++) {
            float v = u2f(p[tid * 4 + k]);
            if (!(v == v) || fabsf(v) > 1e20f) loc = 1;
        }
        if (loc) df = 1;     // benign same-value race
    }
    __syncthreads();
    int isf32 = df;
    if (b < 128) {                      // Wt = Wsoc^T
        unsigned short* Wt = (unsigned short*)(ws + WS_WT);
        int k0 = b * 32;
        if (isf32) {
            const float* W = (const float*)Wsoc;
            #pragma unroll
            for (int p = 0; p < 4; p++) {
                int kk = (tid >> 5) + p * 8, n8 = (tid & 31) * 8;
                #pragma unroll
                for (int q = 0; q < 8; q++)
                    tile[kk * 264 + n8 + q] = f2b(W[(k0 + kk) * 256 + n8 + q]);
            }
        } else {
            const unsigned short* W = (const unsigned short*)Wsoc;
            #pragma unroll
            for (int p = 0; p < 4; p++) {
                int kk = (tid >> 5) + p * 8, n8 = (tid & 31) * 8;
                *(uint4*)&tile[kk * 264 + n8] = *(const uint4*)(W + (k0 + kk) * 256 + n8);
            }
        }
        __syncthreads();
        unsigned int packed[16];
        #pragma unroll
        for (int q = 0; q < 16; q++) {
            unsigned int lo = tile[(2 * q) * 264 + tid];
            unsigned int hi = tile[(2 * q + 1) * 264 + tid];
            packed[q] = lo | (hi << 16);
        }
        uint4* dst = (uint4*)(Wt + (long)tid * 4096 + k0);
        #pragma unroll
        for (int p = 0; p < 4; p++)
            dst[p] = make_uint4(packed[4*p], packed[4*p+1], packed[4*p+2], packed[4*p+3]);
    } else if (b < 140) {               // Wgt = [Wih;Whh]^T
        unsigned short* Wgt = (unsigned short*)(ws + WS_WGT);
        int k0 = (b - 128) * 32;
        #pragma unroll
        for (int p = 0; p < 4; p++) {
            int kk = (tid >> 5) + p * 8, n8 = (tid & 31) * 8;
            int krow = k0 + kk;
            const void* src = (krow < 320) ? Wih : Whh;
            int srow = (krow < 320) ? krow : (krow - 320);
            #pragma unroll
            for (int q = 0; q < 8; q++)
                tile[kk * 264 + n8 + q] = f2b(ldin(src, srow * 256 + n8 + q, isf32));
        }
        __syncthreads();
        unsigned int packed[16];
        #pragma unroll
        for (int q = 0; q < 16; q++) {
            unsigned int lo = tile[(2 * q) * 264 + tid];
            unsigned int hi = tile[(2 * q + 1) * 264 + tid];
            packed[q] = lo | (hi << 16);
        }
        uint4* dst = (uint4*)(Wgt + (long)tid * 384 + k0);
        #pragma unroll
        for (int p = 0; p < 4; p++)
            dst[p] = make_uint4(packed[4*p], packed[4*p+1], packed[4*p+2], packed[4*p+3]);
    } else if (b < 204) {               // Xc f32 from X[...][2:4]
        float* Xc = (float*)(ws + WS_XC);
        #pragma unroll
        for (int p = 0; p < 4; p++) {
            int e = (b - 140) * 1024 + p * 256 + tid;
            int row = e >> 1, comp = e & 1;
            Xc[e] = ldin(X, row * 4 + 2 + comp, isf32);
        }
    } else if (b == 204) {              // consts + flag
        float* bsocF = (float*)(ws + WS_BSOC);
        float* bgF   = (float*)(ws + WS_BG);
        float* WoutF = (float*)(ws + WS_WOUT);
        float* WembF = (float*)(ws + WS_WEMB);
        float* bembF = (float*)(ws + WS_BEMB);
        float* boutF = (float*)(ws + WS_BOUT);
        bsocF[tid] = ldin(bsoc, tid, isf32);
        bgF[tid]   = ldin(bih, tid, isf32) + ldin(bhh, tid, isf32);
        if (tid < 128) { WoutF[tid] = ldin(Wout, tid, isf32); WembF[tid] = ldin(Wemb, tid, isf32); }
        if (tid < 64)  bembF[tid] = ldin(bemb, tid, isf32);
        if (tid < 2)   boutF[tid] = ldin(bout, tid, isf32);
        if (tid == 0)  *(int*)(ws + WS_FLAG) = isf32;
    } else if (b < 221) {               // c0 -> c_ws f32
        float* c_ws = (float*)(ws + WS_CW);
        int base = (b - 205) * 4096 + tid * 16;
        #pragma unroll
        for (int p = 0; p < 16; p++) c_ws[base + p] = ldin(c0, base + p, isf32);
    } else if (b < 229) {               // h0 -> hb0 (bf16)
        unsigned short* hb0 = (unsigned short*)(ws + WS_HB0);
        #pragma unroll
        for (int p = 0; p < 32; p++) {
            int e = (b - 221) * 8192 + p * 256 + tid;
            hb0[e] = f2b(ldin(h0, e, isf32));
        }
    } else {                            // zero d_out (dtype-sized)
        uint4 z = make_uint4(0u, 0u, 0u, 0u);
        uint4* p = (uint4*)out;
        int n16 = isf32 ? 16384 : 8192;
        for (int idx = (b - 229) * 256 + tid; idx < n16; idx += 2048) p[idx] = z;
    }
}

// ---------------- fused per-step kernel (grid 64 x 512) -------------------
__global__ __launch_bounds__(512, 1) void k_fused(char* __restrict__ ws,
                                                  const int* __restrict__ masks,
                                                  const void* __restrict__ Y,
                                                  const int* __restrict__ Tpred,
                                                  void* __restrict__ out,
                                                  int t) {
    int tp = get_tpred(Tpred);
    if (t > tp) return;
    float*          c_ws  = (float*)(ws + WS_CW);
    const unsigned short* Wt  = (const unsigned short*)(ws + WS_WT);
    const unsigned short* Wgt = (const unsigned short*)(ws + WS_WGT);
    const float*    bsocF = (const float*)(ws + WS_BSOC);
    const float*    bgF   = (const float*)(ws + WS_BG);
    const float*    WoutF = (const float*)(ws + WS_WOUT);
    const float*    WembF = (const float*)(ws + WS_WEMB);
    const float*    bembF = (const float*)(ws + WS_BEMB);
    const float*    boutF = (const float*)(ws + WS_BOUT);
    const unsigned short* hbR = (const unsigned short*)(ws + ((t & 1) ? WS_HB1 : WS_HB0));
    unsigned short*       hbW = (unsigned short*)(ws + ((t & 1) ? WS_HB0 : WS_HB1));
    int isf32 = *(const int*)(ws + WS_FLAG);
    int bid = blockIdx.x, tid = threadIdx.x;
    int w = tid >> 6, lane = tid & 63;
    int mrow = lane & 15, q = lane >> 4;
    int row0 = bid * 16;

    // LDS: Hc[16][68] @0 (2176) | z[16][388] @2176 (12416) | Bsm[256][68]
    // @14592 (34816) | jl[8][512] @49408 (8192) = 57600. gbuf f32[16][256]
    // aliases @2176 (over z+Bsm head, both dead by then).
    __shared__ __align__(16) char smem[57600];
    short* Hc  = (short*)smem;
    short* zL  = (short*)(smem + 2176);
    short* Bsm = (short*)(smem + 14592);
    unsigned short* jlW = (unsigned short*)(smem + 49408) + w * 512;
    float* gbuf = (float*)(smem + 2176);

    const float* XcT = (const float*)(ws + WS_XC) + t * 2048;
    const int*   mT  = masks + t * 1024;

    // --- per-row setup: r, h into z; codes into regs (rows w and w+8) -----
    float cix[2], ciy[2]; int mi[2];
    unsigned int cd[2][16];
    #pragma unroll
    for (int rr = 0; rr < 2; rr++) {
        int lr = w + rr * 8, row = row0 + lr;
        cix[rr] = XcT[row * 2]; ciy[rr] = XcT[row * 2 + 1];
        mi[rr]  = mT[row];
        float rv = fmaxf(WembF[lane] * cix[rr] + WembF[64 + lane] * ciy[rr]
                         + bembF[lane], 0.f);
        zL[lr * 388 + lane] = f2b(rv);
        zL[lr * 388 + 320 + lane] = hbR[row * 64 + lane];
    }
    #pragma unroll
    for (int ch = 0; ch < 16; ch++) {
        int j = ch * 64 + lane;
        int mj = mT[j];
        float xj = XcT[j * 2], yj = XcT[j * 2 + 1];
        #pragma unroll
        for (int rr = 0; rr < 2; rr++) {
            int row = row0 + w + rr * 8;
            unsigned int c = 255u;
            if (mi[rr] != 0 && mj != 0 && j != row) {
                int g0 = (int)(xj - cix[rr]);     // trunc == jnp.trunc
                int g1 = (int)(yj - ciy[rr]);
                if (g0 >= -3 && g0 <= 3 && g1 >= -3 && g1 <= 3)
                    c = (unsigned int)((g0 + 3) * 7 + (g1 + 3));
            }
            cd[rr][ch] = c;
        }
    }

    // --- 49-cell loop: stage B slice + gather Hc + MFMA accumulate --------
    f32x4 acc[2];
    f32x4 zz = {0.f, 0.f, 0.f, 0.f};
    acc[0] = zz; acc[1] = zz;
    for (int c = 0; c < 49; c++) {
        int wcell = ((c / 7) * 8 + (c % 7) + 9) * 64;
        {   // stage Bsm: thread -> row n=tid>>1, k-half s2 (32 bf16 = 4 uint4)
            int n = tid >> 1, s2 = (tid & 1) * 32;
            const uint4* s = (const uint4*)(Wt + (long)n * 4096 + wcell + s2);
            uint4* d = (uint4*)&Bsm[n * 68 + s2];
            d[0] = s[0]; d[1] = s[1]; d[2] = s[2]; d[3] = s[3];
        }
        #pragma unroll
        for (int rr = 0; rr < 2; rr++) {
            int lr = w + rr * 8;
            int ntot = 0;
            #pragma unroll
            for (int ch = 0; ch < 16; ch++)
                ntot += (int)__popcll(__ballot(cd[rr][ch] == (unsigned int)c));
            float facc = 0.f;
            if (ntot > 0 && ntot <= 512) {
                int n = 0;
                #pragma unroll
                for (int ch = 0; ch < 16; ch++) {
                    bool p = (cd[rr][ch] == (unsigned int)c);
                    unsigned long long m = __ballot(p);
                    if (p) {
                        int rank = __popcll(m & ((1ull << lane) - 1ull));
                        jlW[n + rank] = (unsigned short)(ch * 64 + lane);
                    }
                    n += (int)__popcll(m);
                }
                int k = 0;
                for (; k + 8 <= n; k += 8) {
                    int j0 = jlW[k], j1 = jlW[k+1], j2 = jlW[k+2], j3 = jlW[k+3];
                    int j4 = jlW[k+4], j5 = jlW[k+5], j6 = jlW[k+6], j7 = jlW[k+7];
                    float v0 = u2f(hbR[j0 * 64 + lane]), v1 = u2f(hbR[j1 * 64 + lane]);
                    float v2 = u2f(hbR[j2 * 64 + lane]), v3 = u2f(hbR[j3 * 64 + lane]);
                    float v4 = u2f(hbR[j4 * 64 + lane]), v5 = u2f(hbR[j5 * 64 + lane]);
                    float v6 = u2f(hbR[j6 * 64 + lane]), v7 = u2f(hbR[j7 * 64 + lane]);
                    facc += ((v0 + v1) + (v2 + v3)) + ((v4 + v5) + (v6 + v7));
                }
                for (; k < n; k++) facc += u2f(hbR[jlW[k] * 64 + lane]);
            } else if (ntot > 512) {      // overflow fallback (cold, correct)
                for (int ch = 0; ch < 16; ch++) {
                    unsigned long long m = __ballot(cd[rr][ch] == (unsigned int)c);
                    while (m) {
                        int jl_ = __ffsll((long long)m) - 1;
                        m &= m - 1;
                        facc += u2f(hbR[(ch * 64 + jl_) * 64 + lane]);
                    }
                }
            }
            Hc[lr * 68 + lane] = f2b(facc);
        }
        __syncthreads();
        #pragma unroll
        for (int kc2 = 0; kc2 < 2; kc2++) {
            bf16x8 af = *(bf16x8*)&Hc[mrow * 68 + kc2 * 32 + q * 8];
            #pragma unroll
            for (int nt = 0; nt < 2; nt++) {
                bf16x8 bv = *(bf16x8*)&Bsm[(w * 32 + nt * 16 + mrow) * 68 + kc2 * 32 + q * 8];
                acc[nt] = __builtin_amdgcn_mfma_f32_16x16x32_bf16(af, bv, acc[nt], 0, 0, 0);
            }
        }
        __syncthreads();
    }

    // --- epre -> z (relu(acc + bsoc), C-layout: col=w*32+nt*16+mrow, row=q*4+r)
    #pragma unroll
    for (int nt = 0; nt < 2; nt++) {
        int col = w * 32 + nt * 16 + mrow;
        float bs = bsocF[col];
        #pragma unroll
        for (int r = 0; r < 4; r++)
            zL[(q * 4 + r) * 388 + 64 + col] = f2b(fmaxf(acc[nt][r] + bs, 0.f));
    }
    __syncthreads();

    // --- gates GEMM: z[16][384] @ Wgt^T, streaming 6 K-slices -------------
    f32x4 acc2[2];
    acc2[0] = zz; acc2[1] = zz;
    for (int kc = 0; kc < 6; kc++) {
        {
            int n = tid >> 1, s2 = (tid & 1) * 32;
            const uint4* s = (const uint4*)(Wgt + (long)n * 384 + kc * 64 + s2);
            uint4* d = (uint4*)&Bsm[n * 68 + s2];
            d[0] = s[0]; d[1] = s[1]; d[2] = s[2]; d[3] = s[3];
        }
        __syncthreads();
        #pragma unroll
        for (int kc2 = 0; kc2 < 2; kc2++) {
            bf16x8 az = *(bf16x8*)&zL[mrow * 388 + kc * 64 + kc2 * 32 + q * 8];
            #pragma unroll
            for (int nt = 0; nt < 2; nt++) {
                bf16x8 bv = *(bf16x8*)&Bsm[(w * 32 + nt * 16 + mrow) * 68 + kc2 * 32 + q * 8];
                acc2[nt] = __builtin_amdgcn_mfma_f32_16x16x32_bf16(az, bv, acc2[nt], 0, 0, 0);
            }
        }
        __syncthreads();
    }

    // --- gates -> gbuf (add biases), then pointwise cell + output ---------
    #pragma unroll
    for (int nt = 0; nt < 2; nt++) {
        int col = w * 32 + nt * 16 + mrow;
        float bg = bgF[col];
        #pragma unroll
        for (int r = 0; r < 4; r++)
            gbuf[(q * 4 + r) * 256 + col] = acc2[nt][r] + bg;
    }
    __syncthreads();
    #pragma unroll
    for (int rr = 0; rr < 2; rr++) {
        int lr = w + rr * 8, row = row0 + lr;
        float gi = gbuf[lr * 256 + lane];
        float gf = gbuf[lr * 256 + 64 + lane];
        float gg = gbuf[lr * 256 + 128 + lane];
        float go = gbuf[lr * 256 + 192 + lane];
        float c  = c_ws[row * 64 + lane];
        float si = 1.f / (1.f + __expf(-gi));
        float sf = 1.f / (1.f + __expf(-gf));
        float so = 1.f / (1.f + __expf(-go));
        float cn = sf * c + si * tanhf(gg);
        float hn = so * tanhf(cn);
        c_ws[row * 64 + lane] = cn;
        hbW[row * 64 + lane] = f2b(hn);
        float p0 = hn * WoutF[lane * 2 + 0];
        float p1 = hn * WoutF[lane * 2 + 1];
        #pragma unroll
        for (int o = 32; o >= 1; o >>= 1) {
            p0 += __shfl_xor(p0, o);
            p1 += __shfl_xor(p1, o);
        }
        if (lane == 0) {
            int m = mT[row];
            float o0 = 0.f, o1 = 0.f;
            if (m != 0) {
                bool appear = (t > 3) && (masks[(t - 3) * 1024 + row] == 0);
                if (appear) {
                    o0 = ldin(Y, (t * 1024 + row) * 2 + 0, isf32);
                    o1 = ldin(Y, (t * 1024 + row) * 2 + 1, isf32);
                } else {
                    o0 = p0 + boutF[0];
                    o1 = p1 + boutF[1];
                }
            }
            if (!(o0 == o0)) o0 = 0.f;
            if (!(o1 == o1)) o1 = 0.f;
            int ofs = (t * 1024 + row) * 2;
            if (isf32) {
                ((float*)out)[ofs + 0] = o0;
                ((float*)out)[ofs + 1] = o1;
            } else {
                ((unsigned short*)out)[ofs + 0] = f2b(o0);
                ((unsigned short*)out)[ofs + 1] = f2b(o1);
            }
        }
    }
}

extern "C" void kernel_launch(void* const* d_in, const int* in_sizes, int n_in,
                              void* d_out, int out_size, void* d_ws, size_t ws_size,
                              hipStream_t stream) {
    (void)in_sizes; (void)n_in; (void)out_size; (void)ws_size;
    const void* X     = d_in[0];
    const int*  masks = (const int*)d_in[1];
    const void* h0    = d_in[2];
    const void* c0    = d_in[3];
    const void* Y     = d_in[4];
    const int*  Tpred = (const int*)d_in[6];
    const void* Wemb  = d_in[7];
    const void* bemb  = d_in[8];
    const void* Wsoc  = d_in[9];
    const void* bsoc  = d_in[10];
    const void* Wih   = d_in[11];
    const void* bih   = d_in[12];
    const void* Whh   = d_in[13];
    const void* bhh   = d_in[14];
    const void* Wout  = d_in[15];
    const void* bout  = d_in[16];

    char* ws = (char*)d_ws;
    k_prep<<<237, 256, 0, stream>>>(ws, X, h0, c0, Wsoc, Wih, Whh, bih, bhh,
                                    bsoc, Wemb, bemb, Wout, bout, d_out);
    for (int t = 0; t < 32; t++) {
        k_fused<<<64, 512, 0, stream>>>(ws, masks, Y, Tpred, d_out, t);
    }
}

// Round 9
// 2100.545 us; speedup vs baseline: 3.2862x; 3.2862x over previous
//
#include <hip/hip_runtime.h>
#include <hip/hip_bf16.h>

// SocialLSTM forward, MI355X gfx950 — 3 kernels/step, latency-tolerant phases.
// k_pool: counting-sort + flat double-buffered gather (1 wave/agent).
// k_gemm: r4-verified 1024-block MFMA K-split. k_cell: 4 rows/block VALU gates.
// ws layout (bytes):
//   c_ws  f32[1024*64]      @ 0
//   Wt    bf16[256][4096]   @ 262144   (W_soc^T, [n][k])
//   Wgt   bf16[256][384]    @ 2359296  ([Wih;Whh]^T, [n][k])
//   bsocF f32[256]          @ 2555904
//   bgF   f32[256]          @ 2556928  (bih+bhh)
//   WoutF f32[128]          @ 2557952
//   WembF f32[128]          @ 2558464
//   bembF f32[64]           @ 2558976
//   boutF f32[2]            @ 2559232
//   flag  int               @ 2559244
//   Xc    f32[32][1024][2]  @ 2560000
//   rbuf  bf16[1024][64]    @ 2822144
//   hb0   bf16[1024][64]    @ 2953216  (h ping)
//   hb1   bf16[1024][64]    @ 3084288  (h pong)
//   Hbuf  bf16[1024][3136]  @ 3215360
//   part  f32[16][1024*256] @ 9637888  (16 MB)

typedef short bf16x8 __attribute__((ext_vector_type(8)));
typedef float f32x4 __attribute__((ext_vector_type(4)));

#define WS_CW    0
#define WS_WT    262144
#define WS_WGT   2359296
#define WS_BSOC  2555904
#define WS_BG    2556928
#define WS_WOUT  2557952
#define WS_WEMB  2558464
#define WS_BEMB  2558976
#define WS_BOUT  2559232
#define WS_FLAG  2559244
#define WS_XC    2560000
#define WS_RBUF  2822144
#define WS_HB0   2953216
#define WS_HB1   3084288
#define WS_HBUF  3215360
#define WS_PART  9637888

__device__ __forceinline__ float u2f(unsigned short u) {
    union { unsigned int i; float f; } v; v.i = ((unsigned int)u) << 16; return v.f;
}
__device__ __forceinline__ unsigned short f2b(float f) {
    __hip_bfloat16 hb = __float2bfloat16(f);
    return *(unsigned short*)&hb;
}
__device__ __forceinline__ float ldin(const void* p, int idx, int isf32) {
    return isf32 ? ((const float*)p)[idx] : u2f(((const unsigned short*)p)[idx]);
}
__device__ __forceinline__ int get_tpred(const int* p) {
    int v = p[0];
    if (v >= 0 && v <= 64) return v;
    float f = ((const float*)p)[0];
    if (f >= 0.f && f <= 64.f) return (int)f;
    float g = u2f(((const unsigned short*)p)[0]);
    if (g >= 0.f && g <= 64.f) return (int)g;
    return 31;
}

// ---------------- one-time prep (237 blocks, inline dtype detect) ---------
__global__ __launch_bounds__(256) void k_prep(char* __restrict__ ws,
                                              const void* __restrict__ X,
                                              const void* __restrict__ h0,
                                              const void* __restrict__ c0,
                                              const void* __restrict__ Wsoc,
                                              const void* __restrict__ Wih,
                                              const void* __restrict__ Whh,
                                              const void* __restrict__ bih,
                                              const void* __restrict__ bhh,
                                              const void* __restrict__ bsoc,
                                              const void* __restrict__ Wemb,
                                              const void* __restrict__ bemb,
                                              const void* __restrict__ Wout,
                                              const void* __restrict__ bout,
                                              void* __restrict__ out) {
    __shared__ __align__(16) unsigned short tile[32 * 264];
    __shared__ int df;
    int b = blockIdx.x, tid = threadIdx.x;
    if (tid == 0) df = 0;
    __syncthreads();
    {
        const unsigned short* p = (const unsigned short*)Wsoc;
        int loc = 0;
        #pragma unroll
        for (int k = 0; k < 4; k++) {
            float v = u2f(p[tid * 4 + k]);
            if (!(v == v) || fabsf(v) > 1e20f) loc = 1;
        }
        if (loc) df = 1;     // benign same-value race
    }
    __syncthreads();
    int isf32 = df;
    if (b < 128) {                      // Wt = Wsoc^T
        unsigned short* Wt = (unsigned short*)(ws + WS_WT);
        int k0 = b * 32;
        if (isf32) {
            const float* W = (const float*)Wsoc;
            #pragma unroll
            for (int p = 0; p < 4; p++) {
                int kk = (tid >> 5) + p * 8, n8 = (tid & 31) * 8;
                #pragma unroll
                for (int q = 0; q < 8; q++)
                    tile[kk * 264 + n8 + q] = f2b(W[(k0 + kk) * 256 + n8 + q]);
            }
        } else {
            const unsigned short* W = (const unsigned short*)Wsoc;
            #pragma unroll
            for (int p = 0; p < 4; p++) {
                int kk = (tid >> 5) + p * 8, n8 = (tid & 31) * 8;
                *(uint4*)&tile[kk * 264 + n8] = *(const uint4*)(W + (k0 + kk) * 256 + n8);
            }
        }
        __syncthreads();
        unsigned int packed[16];
        #pragma unroll
        for (int q = 0; q < 16; q++) {
            unsigned int lo = tile[(2 * q) * 264 + tid];
            unsigned int hi = tile[(2 * q + 1) * 264 + tid];
            packed[q] = lo | (hi << 16);
        }
        uint4* dst = (uint4*)(Wt + (long)tid * 4096 + k0);
        #pragma unroll
        for (int p = 0; p < 4; p++)
            dst[p] = make_uint4(packed[4*p], packed[4*p+1], packed[4*p+2], packed[4*p+3]);
    } else if (b < 140) {               // Wgt = [Wih;Whh]^T
        unsigned short* Wgt = (unsigned short*)(ws + WS_WGT);
        int k0 = (b - 128) * 32;
        #pragma unroll
        for (int p = 0; p < 4; p++) {
            int kk = (tid >> 5) + p * 8, n8 = (tid & 31) * 8;
            int krow = k0 + kk;
            const void* src = (krow < 320) ? Wih : Whh;
            int srow = (krow < 320) ? krow : (krow - 320);
            #pragma unroll
            for (int q = 0; q < 8; q++)
                tile[kk * 264 + n8 + q] = f2b(ldin(src, srow * 256 + n8 + q, isf32));
        }
        __syncthreads();
        unsigned int packed[16];
        #pragma unroll
        for (int q = 0; q < 16; q++) {
            unsigned int lo = tile[(2 * q) * 264 + tid];
            unsigned int hi = tile[(2 * q + 1) * 264 + tid];
            packed[q] = lo | (hi << 16);
        }
        uint4* dst = (uint4*)(Wgt + (long)tid * 384 + k0);
        #pragma unroll
        for (int p = 0; p < 4; p++)
            dst[p] = make_uint4(packed[4*p], packed[4*p+1], packed[4*p+2], packed[4*p+3]);
    } else if (b < 204) {               // Xc f32 from X[...][2:4]
        float* Xc = (float*)(ws + WS_XC);
        #pragma unroll
        for (int p = 0; p < 4; p++) {
            int e = (b - 140) * 1024 + p * 256 + tid;
            int row = e >> 1, comp = e & 1;
            Xc[e] = ldin(X, row * 4 + 2 + comp, isf32);
        }
    } else if (b == 204) {              // consts + flag
        float* bsocF = (float*)(ws + WS_BSOC);
        float* bgF   = (float*)(ws + WS_BG);
        float* WoutF = (float*)(ws + WS_WOUT);
        float* WembF = (float*)(ws + WS_WEMB);
        float* bembF = (float*)(ws + WS_BEMB);
        float* boutF = (float*)(ws + WS_BOUT);
        bsocF[tid] = ldin(bsoc, tid, isf32);
        bgF[tid]   = ldin(bih, tid, isf32) + ldin(bhh, tid, isf32);
        if (tid < 128) { WoutF[tid] = ldin(Wout, tid, isf32); WembF[tid] = ldin(Wemb, tid, isf32); }
        if (tid < 64)  bembF[tid] = ldin(bemb, tid, isf32);
        if (tid < 2)   boutF[tid] = ldin(bout, tid, isf32);
        if (tid == 0)  *(int*)(ws + WS_FLAG) = isf32;
    } else if (b < 221) {               // c0 -> c_ws f32
        float* c_ws = (float*)(ws + WS_CW);
        int base = (b - 205) * 4096 + tid * 16;
        #pragma unroll
        for (int p = 0; p < 16; p++) c_ws[base + p] = ldin(c0, base + p, isf32);
    } else if (b < 229) {               // h0 -> hb0 (bf16)
        unsigned short* hb0 = (unsigned short*)(ws + WS_HB0);
        #pragma unroll
        for (int p = 0; p < 32; p++) {
            int e = (b - 221) * 8192 + p * 256 + tid;
            hb0[e] = f2b(ldin(h0, e, isf32));
        }
    } else {                            // zero d_out (dtype-sized)
        uint4 z = make_uint4(0u, 0u, 0u, 0u);
        uint4* p = (uint4*)out;
        int n16 = isf32 ? 16384 : 8192;
        for (int idx = (b - 229) * 256 + tid; idx < n16; idx += 2048) p[idx] = z;
    }
}

// ---------------- per step: pooling, 1 wave/agent (grid 256) --------------
// counting-sort (hist -> shfl scan -> scatter) then flat 8-deep double-
// buffered gather with register-resident segment boundaries (shfl of scan).
__global__ __launch_bounds__(256) void k_pool(const float* __restrict__ Xc,
                                              const int* __restrict__ masks,
                                              const float* __restrict__ WembF,
                                              const float* __restrict__ bembF,
                                              const int* __restrict__ Tpred,
                                              const unsigned short* __restrict__ hbR,
                                              unsigned short* __restrict__ rbuf,
                                              unsigned short* __restrict__ Hbuf,
                                              int t) {
    if (t > get_tpred(Tpred)) return;
    int tid = threadIdx.x, w = tid >> 6, lane = tid & 63;
    int i = blockIdx.x * 4 + w;
    __shared__ int histS[4][64];
    __shared__ unsigned short jlS[4][1040];
    int* histW = histS[w];
    unsigned short* jlW = jlS[w];
    histW[lane] = 0;
    const float* XcT = Xc + t * 2048;
    const int*   mT  = masks + t * 1024;
    float cix = XcT[i * 2], ciy = XcT[i * 2 + 1];
    int mi = mT[i];
    {   // r = relu(coords @ Wemb + bemb)
        float rv = fmaxf(WembF[lane] * cix + WembF[64 + lane] * ciy + bembF[lane], 0.f);
        rbuf[i * 64 + lane] = f2b(rv);
    }
    int cd[16];
    #pragma unroll
    for (int ch = 0; ch < 16; ch++) {
        int j = ch * 64 + lane;
        int c = -1;
        if (mi != 0 && mT[j] != 0 && j != i) {
            int g0 = (int)(XcT[j * 2]     - cix);   // trunc == jnp.trunc
            int g1 = (int)(XcT[j * 2 + 1] - ciy);
            if (g0 >= -3 && g0 <= 3 && g1 >= -3 && g1 <= 3)
                c = (g0 + 3) * 7 + (g1 + 3);        // dense 0..48
        }
        cd[ch] = c;
    }
    __syncthreads();
    #pragma unroll
    for (int ch = 0; ch < 16; ch++)
        if (cd[ch] >= 0) atomicAdd(&histW[cd[ch]], 1);
    __syncthreads();
    int x = histW[lane];
    int h0v = x;
    #pragma unroll
    for (int off = 1; off < 64; off <<= 1) {
        int y = __shfl_up(x, off);
        if (lane >= off) x += y;
    }
    int excl = x - h0v;                 // exclusive starts, lane c holds st[c]
    __syncthreads();
    histW[lane] = excl;                 // cur = starts
    __syncthreads();
    #pragma unroll
    for (int ch = 0; ch < 16; ch++) {
        if (cd[ch] >= 0) {
            int pos = atomicAdd(&histW[cd[ch]], 1);
            jlW[pos] = (unsigned short)(ch * 64 + lane);
        }
    }
    int ntot = __shfl(excl, 49);
    if (lane < 8) jlW[ntot + lane] = 0; // pad for full batches
    __syncthreads();
    long hb = (long)i * 3136;
    float acc = 0.f;
    int ccur = 0;
    int nxt = __shfl(excl, 1);
    int kiter = (ntot + 7) & ~7;
    float vcur[8];
    #pragma unroll
    for (int u = 0; u < 8; u++) vcur[u] = 0.f;
    if (kiter > 0) {
        #pragma unroll
        for (int u = 0; u < 8; u++) {
            int j = jlW[u];
            vcur[u] = u2f(hbR[j * 64 + lane]);
        }
    }
    for (int k = 0; k < kiter; k += 8) {
        float vnext[8];
        #pragma unroll
        for (int u = 0; u < 8; u++) vnext[u] = 0.f;
        if (k + 8 < kiter) {
            #pragma unroll
            for (int u = 0; u < 8; u++) {
                int j = jlW[k + 8 + u];
                vnext[u] = u2f(hbR[j * 64 + lane]);
            }
        }
        #pragma unroll
        for (int u = 0; u < 8; u++) {
            int idx = k + u;
            while (ccur < 49 && idx == nxt) {   // wave-uniform
                Hbuf[hb + ccur * 64 + lane] = f2b(acc);
                acc = 0.f; ccur++;
                nxt = __shfl(excl, ccur + 1);
            }
            if (idx < ntot) acc += vcur[u];
        }
        #pragma unroll
        for (int u = 0; u < 8; u++) vcur[u] = vnext[u];
    }
    while (ccur < 49) {
        Hbuf[hb + ccur * 64 + lane] = f2b(acc);
        acc = 0.f; ccur++;
    }
}

// ---------------- per step: part[s] = H @ Wsoc slice (grid 1024, MFMA) ----
// r4-verified: ch = bid&3 (64-col slice), s = (bid>>2)&15 (K-split), rb = bid>>6.
__global__ __launch_bounds__(256) void k_gemm(const unsigned short* __restrict__ Hbuf,
                                              const unsigned short* __restrict__ Wt,
                                              const int* __restrict__ Tpred,
                                              float* __restrict__ part,
                                              int t) {
    if (t > get_tpred(Tpred)) return;
    int bid = blockIdx.x, tid = threadIdx.x;
    int ch = bid & 3, s = (bid >> 2) & 15, rb = bid >> 6;
    int row0 = rb * 64, col0 = ch * 64;
    int m0 = 3 * s, m1 = (s == 15) ? 49 : (3 * s + 3);
    __shared__ __align__(16) short Asm[64 * 72];
    __shared__ __align__(16) short Bsm[64 * 72];
    int w = tid >> 6, lane = tid & 63;
    int wrow = (w & 1) * 32, wcol = (w >> 1) * 32;
    int mrow = lane & 15, q = lane >> 4;
    f32x4 acc[2][2];
    f32x4 zz = {0.f, 0.f, 0.f, 0.f};
    acc[0][0] = zz; acc[0][1] = zz; acc[1][0] = zz; acc[1][1] = zz;
    for (int m = m0; m < m1; m++) {
        int wcell = ((m / 7) * 8 + (m % 7) + 9) * 64;
        __syncthreads();
        {
            int row = tid >> 2;
            #pragma unroll
            for (int p = 0; p < 2; p++) {
                int seg = (tid & 3) + (p << 2);
                *(uint4*)&Asm[row * 72 + seg * 8] =
                    *(const uint4*)(Hbuf + (long)(row0 + row) * 3136 + m * 64 + seg * 8);
                *(uint4*)&Bsm[row * 72 + seg * 8] =
                    *(const uint4*)(Wt + (long)(col0 + row) * 4096 + wcell + seg * 8);
            }
        }
        __syncthreads();
        #pragma unroll
        for (int kc = 0; kc < 2; kc++) {
            bf16x8 a0 = *(bf16x8*)&Asm[(wrow +      mrow) * 72 + kc * 32 + q * 8];
            bf16x8 a1 = *(bf16x8*)&Asm[(wrow + 16 + mrow) * 72 + kc * 32 + q * 8];
            #pragma unroll
            for (int ct = 0; ct < 2; ct++) {
                bf16x8 bv = *(bf16x8*)&Bsm[(wcol + ct * 16 + mrow) * 72 + kc * 32 + q * 8];
                acc[0][ct] = __builtin_amdgcn_mfma_f32_16x16x32_bf16(a0, bv, acc[0][ct], 0, 0, 0);
                acc[1][ct] = __builtin_amdgcn_mfma_f32_16x16x32_bf16(a1, bv, acc[1][ct], 0, 0, 0);
            }
        }
    }
    float* ps = part + (long)s * 262144;
    #pragma unroll
    for (int rt = 0; rt < 2; rt++)
        #pragma unroll
        for (int ct = 0; ct < 2; ct++)
            #pragma unroll
            for (int r = 0; r < 4; r++) {
                int grow = row0 + wrow + rt * 16 + q * 4 + r;
                int gcol = col0 + wcol + ct * 16 + mrow;
                ps[grow * 256 + gcol] = acc[rt][ct][r];
            }
}

// ---------------- per step: part-reduce + gates + cell + out (grid 256) ---
__global__ __launch_bounds__(256) void k_cell(const int* __restrict__ masks,
                                              const void* __restrict__ Y,
                                              const float* __restrict__ part,
                                              const unsigned short* __restrict__ Wgt,
                                              const float* __restrict__ bsocF,
                                              const float* __restrict__ bgF,
                                              const float* __restrict__ WoutF,
                                              const float* __restrict__ boutF,
                                              float* __restrict__ c_ws,
                                              const unsigned short* __restrict__ rbuf,
                                              const unsigned short* __restrict__ hbR,
                                              unsigned short* __restrict__ hbW,
                                              const int* __restrict__ Tpred,
                                              const int* __restrict__ flag,
                                              void* __restrict__ out,
                                              int t) {
    if (t > get_tpred(Tpred)) return;
    int isf32 = flag[0];
    int bid = blockIdx.x, tid = threadIdx.x;
    int w = tid >> 6, lane = tid & 63;
    int row0 = bid * 4;
    __shared__ __align__(16) float zF[4][384];
    __shared__ float gbuf[4][256];
    // stage r, h (1 elem/thread each) and e (4 cols/thread, 16-part reduce)
    zF[w][lane]       = u2f(rbuf[(row0 + w) * 64 + lane]);
    zF[w][320 + lane] = u2f(hbR[(row0 + w) * 64 + lane]);
    {
        int c4 = lane * 4;
        float4 a = *(const float4*)(bsocF + c4);
        #pragma unroll
        for (int ss = 0; ss < 16; ss++) {
            float4 u = *(const float4*)(part + (long)ss * 262144 + (row0 + w) * 256 + c4);
            a.x += u.x; a.y += u.y; a.z += u.z; a.w += u.w;
        }
        zF[w][64 + c4 + 0] = fmaxf(a.x, 0.f);
        zF[w][64 + c4 + 1] = fmaxf(a.y, 0.f);
        zF[w][64 + c4 + 2] = fmaxf(a.z, 0.f);
        zF[w][64 + c4 + 3] = fmaxf(a.w, 0.f);
    }
    __syncthreads();
    // gates: thread tid = output col n; 4 rows; stream Wgt row n (48 uint4)
    float a0 = 0.f, a1 = 0.f, a2 = 0.f, a3 = 0.f;
    const unsigned short* wr = Wgt + (long)tid * 384;
    for (int k8 = 0; k8 < 48; k8++) {
        uint4 wv = *(const uint4*)(wr + k8 * 8);
        float wf[8];
        wf[0] = u2f((unsigned short)(wv.x & 0xFFFFu)); wf[1] = u2f((unsigned short)(wv.x >> 16));
        wf[2] = u2f((unsigned short)(wv.y & 0xFFFFu)); wf[3] = u2f((unsigned short)(wv.y >> 16));
        wf[4] = u2f((unsigned short)(wv.z & 0xFFFFu)); wf[5] = u2f((unsigned short)(wv.z >> 16));
        wf[6] = u2f((unsigned short)(wv.w & 0xFFFFu)); wf[7] = u2f((unsigned short)(wv.w >> 16));
        #pragma unroll
        for (int r = 0; r < 4; r++) {
            float4 z0 = *(const float4*)&zF[r][k8 * 8];
            float4 z1 = *(const float4*)&zF[r][k8 * 8 + 4];
            float s0 = z0.x * wf[0] + z0.y * wf[1] + z0.z * wf[2] + z0.w * wf[3];
            float s1 = z1.x * wf[4] + z1.y * wf[5] + z1.z * wf[6] + z1.w * wf[7];
            float sr = s0 + s1;
            if (r == 0) a0 += sr; else if (r == 1) a1 += sr;
            else if (r == 2) a2 += sr; else a3 += sr;
        }
    }
    {
        float bg = bgF[tid];
        gbuf[0][tid] = a0 + bg; gbuf[1][tid] = a1 + bg;
        gbuf[2][tid] = a2 + bg; gbuf[3][tid] = a3 + bg;
    }
    __syncthreads();
    // pointwise cell + output: wave w owns row row0+w
    {
        int row = row0 + w;
        float gi = gbuf[w][lane];
        float gf = gbuf[w][64 + lane];
        float gg = gbuf[w][128 + lane];
        float go = gbuf[w][192 + lane];
        float c  = c_ws[row * 64 + lane];
        float si = 1.f / (1.f + __expf(-gi));
        float sf = 1.f / (1.f + __expf(-gf));
        float so = 1.f / (1.f + __expf(-go));
        float cn = sf * c + si * tanhf(gg);
        float hn = so * tanhf(cn);
        c_ws[row * 64 + lane] = cn;
        hbW[row * 64 + lane] = f2b(hn);
        float p0 = hn * WoutF[lane * 2 + 0];
        float p1 = hn * WoutF[lane * 2 + 1];
        #pragma unroll
        for (int o = 32; o >= 1; o >>= 1) {
            p0 += __shfl_xor(p0, o);
            p1 += __shfl_xor(p1, o);
        }
        if (lane == 0) {
            int m = masks[t * 1024 + row];
            float o0 = 0.f, o1 = 0.f;
            if (m != 0) {
                bool appear = (t > 3) && (masks[(t - 3) * 1024 + row] == 0);
                if (appear) {
                    o0 = ldin(Y, (t * 1024 + row) * 2 + 0, isf32);
                    o1 = ldin(Y, (t * 1024 + row) * 2 + 1, isf32);
                } else {
                    o0 = p0 + boutF[0];
                    o1 = p1 + boutF[1];
                }
            }
            if (!(o0 == o0)) o0 = 0.f;
            if (!(o1 == o1)) o1 = 0.f;
            int ofs = (t * 1024 + row) * 2;
            if (isf32) {
                ((float*)out)[ofs + 0] = o0;
                ((float*)out)[ofs + 1] = o1;
            } else {
                ((unsigned short*)out)[ofs + 0] = f2b(o0);
                ((unsigned short*)out)[ofs + 1] = f2b(o1);
            }
        }
    }
}

extern "C" void kernel_launch(void* const* d_in, const int* in_sizes, int n_in,
                              void* d_out, int out_size, void* d_ws, size_t ws_size,
                              hipStream_t stream) {
    (void)in_sizes; (void)n_in; (void)out_size; (void)ws_size;
    const void* X     = d_in[0];
    const int*  masks = (const int*)d_in[1];
    const void* h0    = d_in[2];
    const void* c0    = d_in[3];
    const void* Y     = d_in[4];
    const int*  Tpred = (const int*)d_in[6];
    const void* Wemb  = d_in[7];
    const void* bemb  = d_in[8];
    const void* Wsoc  = d_in[9];
    const void* bsoc  = d_in[10];
    const void* Wih   = d_in[11];
    const void* bih   = d_in[12];
    const void* Whh   = d_in[13];
    const void* bhh   = d_in[14];
    const void* Wout  = d_in[15];
    const void* bout  = d_in[16];

    char* ws = (char*)d_ws;
    int*            flag  = (int*)(ws + WS_FLAG);
    float*          c_ws  = (float*)(ws + WS_CW);
    unsigned short* Wt    = (unsigned short*)(ws + WS_WT);
    unsigned short* Wgt   = (unsigned short*)(ws + WS_WGT);
    const float*    bsocF = (const float*)(ws + WS_BSOC);
    const float*    bgF   = (const float*)(ws + WS_BG);
    const float*    WoutF = (const float*)(ws + WS_WOUT);
    const float*    WembF = (const float*)(ws + WS_WEMB);
    const float*    bembF = (const float*)(ws + WS_BEMB);
    const float*    boutF = (const float*)(ws + WS_BOUT);
    const float*    Xc    = (const float*)(ws + WS_XC);
    unsigned short* rbuf  = (unsigned short*)(ws + WS_RBUF);
    unsigned short* Hbuf  = (unsigned short*)(ws + WS_HBUF);
    float*          part  = (float*)(ws + WS_PART);

    k_prep<<<237, 256, 0, stream>>>(ws, X, h0, c0, Wsoc, Wih, Whh, bih, bhh,
                                    bsoc, Wemb, bemb, Wout, bout, d_out);
    for (int t = 0; t < 32; t++) {
        unsigned short* hbR = (unsigned short*)(ws + ((t & 1) ? WS_HB1 : WS_HB0));
        unsigned short* hbW = (unsigned short*)(ws + ((t & 1) ? WS_HB0 : WS_HB1));
        k_pool<<<256, 256, 0, stream>>>(Xc, masks, WembF, bembF, Tpred,
                                        hbR, rbuf, Hbuf, t);
        k_gemm<<<1024, 256, 0, stream>>>(Hbuf, Wt, Tpred, part, t);
        k_cell<<<256, 256, 0, stream>>>(masks, Y, part, Wgt, bsocF, bgF, WoutF,
                                        boutF, c_ws, rbuf, hbR, hbW, Tpred, flag,
                                        d_out, t);
    }
}